// Round 10
// baseline (411.402 us; speedup 1.0000x reference)
//
#include <hip/hip_runtime.h>
#include <math.h>

typedef __attribute__((ext_vector_type(8))) short bfrag;
typedef __attribute__((ext_vector_type(4))) float ffrag;

namespace {
constexpr int Sc = 1024, Dc = 64;
constexpr int P2 = 72;          // bf16 LDS pitch (144 B) for MFMA-read tiles
constexpr int PQ = 64;          // Qs pitch — hoist read is one-time, no pad needed
constexpr int PW = 33;          // f32 pitch for Ts/Ws — bank-spread for row reads
constexpr float S2 = 0.125f * 1.44269504088896f; // SCALE * log2(e)
}

__device__ __forceinline__ unsigned short f2bf(float f) {
    unsigned u = __builtin_bit_cast(unsigned, f);
    u += 0x7fffu + ((u >> 16) & 1u);
    return (unsigned short)(u >> 16);
}
__device__ __forceinline__ bfrag pack8(float4 a, float4 b) {
    bfrag r;
    r[0] = (short)f2bf(a.x); r[1] = (short)f2bf(a.y);
    r[2] = (short)f2bf(a.z); r[3] = (short)f2bf(a.w);
    r[4] = (short)f2bf(b.x); r[5] = (short)f2bf(b.y);
    r[6] = (short)f2bf(b.z); r[7] = (short)f2bf(b.w);
    return r;
}
#define MFMA(a, b, c) __builtin_amdgcn_mfma_f32_16x16x32_bf16((a), (b), (c), 0, 0, 0)

// Pass 1 is BARRIER-FREE: each wave loads its own K MFMA B-fragments straight
// from global (lane (n,quad) reads K[row][quad*8..] — fragment layout needs no
// cross-lane exchange), so the K-tile LDS staging and its 17 barrier-windows
// vanish; 8 free-running waves/CU hide the L2-hot load latency.
// Pass 2 unchanged from R9: pipelined QK(kt) || PV(kt-1)+dump, 1 barrier/kt.
__global__ __launch_bounds__(256, 2)
void relattn(const float* __restrict__ Qg, const float* __restrict__ Kg,
             const float* __restrict__ Vg, const float* __restrict__ pek,
             const float* __restrict__ pev, float* __restrict__ outg,
             float* __restrict__ pbuf)
{
    // LDS arena (72448 B, 2 blocks/CU):
    // Ks0 9216 | Ks1 9216 | Vt0 9216 | Vt1 9216 | Pt0 9216 | Pt1 9216 |
    // Ts 8448 | QsArena 8704 (Qs [64][64] bf16 aliased by Ws [64][33] f32 + W0 [64])
    // Ot (64x68 f32 = 17408 B) aliases Ks0+Ks1 (epilogue only).
    __shared__ __align__(16) char smem[72448];
    unsigned short* Ks0 = (unsigned short*)smem;
    unsigned short* Ks1 = (unsigned short*)(smem + 9216);
    unsigned short* Vt0 = (unsigned short*)(smem + 18432);
    unsigned short* Vt1 = (unsigned short*)(smem + 27648);
    unsigned short* Pt0 = (unsigned short*)(smem + 36864);
    unsigned short* Pt1 = (unsigned short*)(smem + 46080);
    float* Ts = (float*)(smem + 55296);                    // [64][33]
    unsigned short* Qs = (unsigned short*)(smem + 63744);  // [64][64]
    float* Ws = (float*)(smem + 63744);                    // [64][33], aliases Qs
    float* W0 = (float*)(smem + 72192);                    // [64]
    float* Ot = (float*)smem;                              // [64][68], aliases Ks0+Ks1

    const int tid  = threadIdx.x;
    const int bh   = blockIdx.y;
    const int wv   = tid >> 6;
    const int lane = tid & 63;
    const int n    = lane & 15;
    const int quad = lane >> 4;

    const float* Qbh = Qg + (size_t)bh * Sc * Dc;
    const float* Kbh = Kg + (size_t)bh * Sc * Dc;
    const float* Vbh = Vg + (size_t)bh * Sc * Dc;
    float* pbh = pbuf + (size_t)bh * Sc * Sc;
    float* obh = outg + (size_t)bh * Sc * Dc;

    const int sr  = tid >> 2;           // staging row 0..63
    const int sc4 = (tid & 3) * 16;     // staging col (floats)
    const int kp  = tid & 31;           // V-transpose k-pair
    const int vd0 = (tid >> 5) * 8;     // V-transpose d base

    // dump-phase coords: thread owns float4 col c4 of rows {rr, 16+rr, 32+rr, 48+rr}
    const int rr = tid >> 4;            // 0..15
    const int c4 = tid & 15;            // 0..15 (float4 col)

    for (int half = 0; half < 2; ++half) {
        const int qt = half ? (15 - (int)blockIdx.x) : (int)blockIdx.x;
        const int qrow = wv * 16 + quad * 4;   // C-layout row base for this lane

        __syncthreads();   // previous half's epilogue fully done with LDS

        // ---- stage Q tile (fp32 -> bf16) ----
        {
            const float* src = Qbh + (size_t)(qt * 64 + sr) * Dc + sc4;
            float4 a = *(const float4*)(src);
            float4 b = *(const float4*)(src + 4);
            float4 c = *(const float4*)(src + 8);
            float4 d = *(const float4*)(src + 12);
            *(bfrag*)&Qs[sr * PQ + sc4]     = pack8(a, b);
            *(bfrag*)&Qs[sr * PQ + sc4 + 8] = pack8(c, d);
        }
        // ---- stage pe_k (rows 0..32) into Ks0; zero rows 33..47 ----
        for (int i = tid; i < 135; i += 256) {          // zero [33*72, 48*72)
            bfrag z = {};
            *(bfrag*)&Ks0[33 * P2 + i * 8] = z;
        }
        if (tid < 132) {
            int r = tid >> 2, c0 = (tid & 3) * 16;
            const float* src = pek + (size_t)r * Dc + c0;
            float4 a = *(const float4*)(src);
            float4 b = *(const float4*)(src + 4);
            float4 c = *(const float4*)(src + 8);
            float4 d = *(const float4*)(src + 12);
            *(bfrag*)&Ks0[r * P2 + c0]     = pack8(a, b);
            *(bfrag*)&Ks0[r * P2 + c0 + 8] = pack8(c, d);
        }
        __syncthreads();

        // ---- hoist Q A-frags (row = wv*16+n, k = d); Qs dead afterwards ----
        bfrag qa0 = *(bfrag*)&Qs[(wv * 16 + n) * PQ + quad * 8];
        bfrag qa1 = *(bfrag*)&Qs[(wv * 16 + n) * PQ + 32 + quad * 8];

        // ---- Ts = Q . pe_k^T via MFMA (j in 0..47, keep j<=32) ----
        #pragma unroll
        for (int sub = 0; sub < 3; ++sub) {
            bfrag b0 = *(bfrag*)&Ks0[(sub * 16 + n) * P2 + quad * 8];
            bfrag b1 = *(bfrag*)&Ks0[(sub * 16 + n) * P2 + 32 + quad * 8];
            ffrag c = {};
            c = MFMA(qa0, b0, c);
            c = MFMA(qa1, b1, c);
            int j = sub * 16 + n;
            if (j <= 32) {
                #pragma unroll
                for (int reg = 0; reg < 4; ++reg)
                    Ts[(qrow + reg) * PW + j] = c[reg];
            }
        }
        __syncthreads();   // Ts visible; pe_k (Ks0) dead; Qs hoisted -> free

        float ts2[4];   // pre-scaled for exp2: exp((c+ts0)*SCALE) = exp2(fma(c,S2,ts2))
        #pragma unroll
        for (int reg = 0; reg < 4; ++reg) ts2[reg] = Ts[(qrow + reg) * PW] * S2;

        // ---- zero Ws (aliases Qs; safe after barrier) ----
        for (int idx = tid; idx < 64 * PW; idx += 256) Ws[idx] = 0.f;

        // ---- zero-fill fully-masked p region (cols >= (qt+1)*64) ----
        {
            const int zb = (qt + 1) * 64;
            if (zb < Sc) {
                const int z4 = (Sc - zb) >> 2;
                const float4 z = make_float4(0.f, 0.f, 0.f, 0.f);
                for (int r = 0; r < 64; ++r) {
                    float4* rp = (float4*)(pbh + (size_t)(qt * 64 + r) * Sc + zb);
                    for (int cz = tid; cz < z4; cz += 256) rp[cz] = z;
                }
            }
        }

        // ===== pass 1: l = sum(exp(s)) — BARRIER-FREE, K frags from global =====
        float lsum[4] = {0.f, 0.f, 0.f, 0.f};
        {
            // lane's fragment base: row n, d-cols quad*8 (b0) / 32+quad*8 (b1)
            const float* kfp = Kbh + (size_t)n * Dc + quad * 8;
            for (int kt = 0; kt <= qt; ++kt) {
                const bool bnd = (kt >= qt - 1);
                const float* kpt = kfp + (size_t)(kt * 64) * Dc;
                float4 r0[4], r1[4], r2[4], r3[4];   // [sub]: b0lo,b0hi,b1lo,b1hi
                #pragma unroll
                for (int s = 0; s < 4; ++s) {
                    const float* ps = kpt + (size_t)(s * 16) * Dc;
                    r0[s] = *(const float4*)(ps);
                    r1[s] = *(const float4*)(ps + 4);
                    r2[s] = *(const float4*)(ps + 32);
                    r3[s] = *(const float4*)(ps + 36);
                }
                #pragma unroll
                for (int s = 0; s < 4; ++s) {
                    bfrag b0 = pack8(r0[s], r1[s]);
                    bfrag b1 = pack8(r2[s], r3[s]);
                    ffrag c = {};
                    c = MFMA(qa0, b0, c);
                    c = MFMA(qa1, b1, c);
                    const int k = kt * 64 + s * 16 + n;
                    if (!bnd) {
                        #pragma unroll
                        for (int reg = 0; reg < 4; ++reg)
                            lsum[reg] += exp2f(fmaf(c[reg], S2, ts2[reg]));
                    } else {
                        #pragma unroll
                        for (int reg = 0; reg < 4; ++reg) {
                            int jrel = k - (qt * 64 + qrow + reg) + 32;
                            if (jrel <= 32) {
                                int jcl = jrel < 0 ? 0 : jrel;
                                lsum[reg] += exp2f(fmaf(c[reg] + Ts[(qrow + reg) * PW + jcl], S2, 0.f));
                            }
                        }
                    }
                }
            }
        }
        float rinv[4];
        #pragma unroll
        for (int reg = 0; reg < 4; ++reg) {
            float l = lsum[reg];
            l += __shfl_xor(l, 1);
            l += __shfl_xor(l, 2);
            l += __shfl_xor(l, 4);
            l += __shfl_xor(l, 8);
            rinv[reg] = 1.f / l;
        }

        // ---- pass-2 prologue: stage K[0]->Ks0 (L2-hot); issue K[1], V[0] ----
        {
            const float* ksrc = Kbh + (size_t)sr * Dc + sc4;
            float4 a = *(const float4*)(ksrc);
            float4 b = *(const float4*)(ksrc + 4);
            float4 c = *(const float4*)(ksrc + 8);
            float4 d = *(const float4*)(ksrc + 12);
            *(bfrag*)&Ks0[sr * P2 + sc4]     = pack8(a, b);
            *(bfrag*)&Ks0[sr * P2 + sc4 + 8] = pack8(c, d);
        }
        float4 pka, pkb, pkc, pkd;
        if (qt >= 1) {
            const float* ksrc = Kbh + (size_t)(64 + sr) * Dc + sc4;
            pka = *(const float4*)(ksrc);
            pkb = *(const float4*)(ksrc + 4);
            pkc = *(const float4*)(ksrc + 8);
            pkd = *(const float4*)(ksrc + 12);
        }
        float4 pva, pvb, pvc, pvd;
        {
            const float* vsrc = Vbh + (size_t)(2 * kp) * Dc + vd0;
            pva = *(const float4*)(vsrc);
            pvb = *(const float4*)(vsrc + 4);
            pvc = *(const float4*)(vsrc + Dc);
            pvd = *(const float4*)(vsrc + Dc + 4);
        }
        __syncthreads();   // K[0] visible

        // ====== pass 2 (pipelined, 1 barrier/kt): QK(kt) || PV(kt-1)+dump ======
        ffrag oacc[4];
        #pragma unroll
        for (int i = 0; i < 4; ++i) { ffrag z = {}; oacc[i] = z; }

        for (int kt = 0; kt <= qt; ++kt) {
            const bool bnd = (kt >= qt - 1);
            unsigned short* Kc  = (kt & 1) ? Ks1 : Ks0;   // K[kt] (K[0] in Ks0)
            unsigned short* Kn  = (kt & 1) ? Ks0 : Ks1;
            unsigned short* Vc  = (kt & 1) ? Vt1 : Vt0;   // stage target for V[kt]
            unsigned short* Vp  = (kt & 1) ? Vt0 : Vt1;   // V[kt-1] for PV
            unsigned short* Ptc = (kt & 1) ? Pt1 : Pt0;   // QK(kt) writes
            unsigned short* Ptp = (kt & 1) ? Pt0 : Pt1;   // PV(kt-1) reads

            // ---- QK(kt): scores -> Ptc (bf16, normalized), rel-v capture ----
            #pragma unroll
            for (int sub = 0; sub < 4; ++sub) {
                bfrag b0 = *(bfrag*)&Kc[(sub * 16 + n) * P2 + quad * 8];
                bfrag b1 = *(bfrag*)&Kc[(sub * 16 + n) * P2 + 32 + quad * 8];
                ffrag c = {};
                c = MFMA(qa0, b0, c);
                c = MFMA(qa1, b1, c);
                const int k = kt * 64 + sub * 16 + n;
                if (!bnd) {
                    #pragma unroll
                    for (int reg = 0; reg < 4; ++reg) {
                        float p = exp2f(fmaf(c[reg], S2, ts2[reg])) * rinv[reg];
                        Ptc[(qrow + reg) * P2 + sub * 16 + n] = (unsigned short)f2bf(p);
                    }
                } else {
                    #pragma unroll
                    for (int reg = 0; reg < 4; ++reg) {
                        int jrel = k - (qt * 64 + qrow + reg) + 32;
                        float p = 0.f;
                        if (jrel <= 32) {
                            int jcl = jrel < 0 ? 0 : jrel;
                            p = exp2f((c[reg] + Ts[(qrow + reg) * PW + jcl]) * S2) * rinv[reg];
                        }
                        Ptc[(qrow + reg) * P2 + sub * 16 + n] = (unsigned short)f2bf(p);
                        if ((unsigned)(jrel - 1) < 32u) Ws[(qrow + reg) * PW + jrel - 1] = p;
                    }
                }
            }
            // ---- stage K[kt+1] -> Kn; V[kt] -> Vc (regs from last window) ----
            if (kt < qt) {
                *(bfrag*)&Kn[sr * P2 + sc4]     = pack8(pka, pkb);
                *(bfrag*)&Kn[sr * P2 + sc4 + 8] = pack8(pkc, pkd);
            }
            {
                float r0[8] = {pva.x, pva.y, pva.z, pva.w, pvb.x, pvb.y, pvb.z, pvb.w};
                float r1[8] = {pvc.x, pvc.y, pvc.z, pvc.w, pvd.x, pvd.y, pvd.z, pvd.w};
                #pragma unroll
                for (int i = 0; i < 8; ++i) {
                    unsigned pk2 = (unsigned)f2bf(r0[i]) | ((unsigned)f2bf(r1[i]) << 16);
                    *(unsigned*)&Vc[(vd0 + i) * P2 + 2 * kp] = pk2;   // Vc[d][k]
                }
            }
            // ---- issue next prefetches ----
            if (kt + 2 <= qt) {
                const float* ksrc = Kbh + (size_t)((kt + 2) * 64 + sr) * Dc + sc4;
                pka = *(const float4*)(ksrc);
                pkb = *(const float4*)(ksrc + 4);
                pkc = *(const float4*)(ksrc + 8);
                pkd = *(const float4*)(ksrc + 12);
            }
            if (kt + 1 <= qt) {
                const float* vsrc = Vbh + (size_t)((kt + 1) * 64 + 2 * kp) * Dc + vd0;
                pva = *(const float4*)(vsrc);
                pvb = *(const float4*)(vsrc + 4);
                pvc = *(const float4*)(vsrc + Dc);
                pvd = *(const float4*)(vsrc + Dc + 4);
            }
            // ---- PV(kt-1) + dump(kt-1): independent of QK(kt) ----
            if (kt >= 1) {
                bfrag pb0 = *(bfrag*)&Ptp[(wv * 16 + n) * P2 + quad * 8];
                bfrag pb1 = *(bfrag*)&Ptp[(wv * 16 + n) * P2 + 32 + quad * 8];
                #pragma unroll
                for (int ds = 0; ds < 4; ++ds) {
                    bfrag va0 = *(bfrag*)&Vp[(ds * 16 + n) * P2 + quad * 8];
                    bfrag va1 = *(bfrag*)&Vp[(ds * 16 + n) * P2 + 32 + quad * 8];
                    oacc[ds] = MFMA(va0, pb0, oacc[ds]);
                    oacc[ds] = MFMA(va1, pb1, oacc[ds]);
                }
                float* base = pbh + ((size_t)(qt * 64 + rr) * Sc + (kt - 1) * 64 + c4 * 4);
                #pragma unroll
                for (int step = 0; step < 4; ++step) {
                    const int r = step * 16 + rr;
                    uint2 two = *(const uint2*)&Ptp[r * P2 + c4 * 4];   // ds_read_b64
                    float4 v;
                    v.x = __builtin_bit_cast(float, (two.x & 0xffffu) << 16);
                    v.y = __builtin_bit_cast(float, two.x & 0xffff0000u);
                    v.z = __builtin_bit_cast(float, (two.y & 0xffffu) << 16);
                    v.w = __builtin_bit_cast(float, two.y & 0xffff0000u);
                    *(float4*)(base + (size_t)(step * 16) * Sc) = v;
                }
            }
            __syncthreads();   // window boundary
        }
        // ---- drain: PV(qt) + dump(qt) ----
        {
            unsigned short* Ptp = (qt & 1) ? Pt1 : Pt0;
            unsigned short* Vp  = (qt & 1) ? Vt1 : Vt0;
            bfrag pb0 = *(bfrag*)&Ptp[(wv * 16 + n) * P2 + quad * 8];
            bfrag pb1 = *(bfrag*)&Ptp[(wv * 16 + n) * P2 + 32 + quad * 8];
            #pragma unroll
            for (int ds = 0; ds < 4; ++ds) {
                bfrag va0 = *(bfrag*)&Vp[(ds * 16 + n) * P2 + quad * 8];
                bfrag va1 = *(bfrag*)&Vp[(ds * 16 + n) * P2 + 32 + quad * 8];
                oacc[ds] = MFMA(va0, pb0, oacc[ds]);
                oacc[ds] = MFMA(va1, pb1, oacc[ds]);
            }
            float* base = pbh + ((size_t)(qt * 64 + rr) * Sc + qt * 64 + c4 * 4);
            #pragma unroll
            for (int step = 0; step < 4; ++step) {
                const int r = step * 16 + rr;
                uint2 two = *(const uint2*)&Ptp[r * P2 + c4 * 4];   // ds_read_b64
                float4 v;
                v.x = __builtin_bit_cast(float, (two.x & 0xffffu) << 16);
                v.y = __builtin_bit_cast(float, two.x & 0xffff0000u);
                v.z = __builtin_bit_cast(float, (two.y & 0xffffu) << 16);
                v.w = __builtin_bit_cast(float, two.y & 0xffff0000u);
                *(float4*)(base + (size_t)(step * 16) * Sc) = v;
            }
        }
        __syncthreads();   // all PV/dump reads done before epilogue prep writes

        // ================= epilogue: rel-v term + store O =================
        if (tid < 64) {
            float s = 0.f;
            #pragma unroll
            for (int j = 0; j < 32; ++j) s += Ws[tid * PW + j];   // pitch-33: conflict-free
            W0[tid] = 1.f - s;   // mass of far past (jrel<=0)
        }
        {   // Pt0[q][jj] <- Ws (bf16), jj = jrel-1 in 0..31
            int q = tid >> 2, j0 = (tid & 3) * 8;
            #pragma unroll
            for (int i = 0; i < 8; i += 2) {
                unsigned pk2 = (unsigned)f2bf(Ws[q * PW + j0 + i]) |
                               ((unsigned)f2bf(Ws[q * PW + j0 + i + 1]) << 16);
                *(unsigned*)&Pt0[q * P2 + j0 + i] = pk2;
            }
        }
        {   // Vt0[d][jj] <- pe_v[jj+1][d]
            int jj = tid >> 3, d0 = (tid & 7) * 8;
            const float* src = pev + (size_t)(jj + 1) * Dc + d0;
            float4 a = *(const float4*)(src);
            float4 b = *(const float4*)(src + 4);
            float vr[8] = {a.x, a.y, a.z, a.w, b.x, b.y, b.z, b.w};
            #pragma unroll
            for (int i = 0; i < 8; ++i)
                Vt0[(d0 + i) * P2 + jj] = (unsigned short)f2bf(vr[i]);
        }
        __syncthreads();   // Pt0/Vt0/W0 prep visible
        {
            bfrag pb = *(bfrag*)&Pt0[(wv * 16 + n) * P2 + quad * 8];
            #pragma unroll
            for (int ds = 0; ds < 4; ++ds) {
                bfrag va = *(bfrag*)&Vt0[(ds * 16 + n) * P2 + quad * 8];
                oacc[ds] = MFMA(va, pb, oacc[ds]);
            }
        }
        float w0q = W0[wv * 16 + n];
        // Ot aliases Ks0/Ks1 only (dead) — no barrier needed before write
        #pragma unroll
        for (int ds = 0; ds < 4; ++ds) {
            float4 ov;
            ov.x = oacc[ds][0] + w0q * pev[ds * 16 + quad * 4 + 0];
            ov.y = oacc[ds][1] + w0q * pev[ds * 16 + quad * 4 + 1];
            ov.z = oacc[ds][2] + w0q * pev[ds * 16 + quad * 4 + 2];
            ov.w = oacc[ds][3] + w0q * pev[ds * 16 + quad * 4 + 3];
            *(float4*)&Ot[(wv * 16 + n) * 68 + ds * 16 + quad * 4] = ov;
        }
        __syncthreads();
        {
            int r = tid >> 2, c0 = (tid & 3) * 16;
            float* dst = obh + (size_t)(qt * 64 + r) * Dc + c0;
            *(float4*)(dst)      = *(float4*)&Ot[r * 68 + c0];
            *(float4*)(dst + 4)  = *(float4*)&Ot[r * 68 + c0 + 4];
            *(float4*)(dst + 8)  = *(float4*)&Ot[r * 68 + c0 + 8];
            *(float4*)(dst + 12) = *(float4*)&Ot[r * 68 + c0 + 12];
        }
    }
}

extern "C" void kernel_launch(void* const* d_in, const int* in_sizes, int n_in,
                              void* d_out, int out_size, void* d_ws, size_t ws_size,
                              hipStream_t stream)
{
    const float* Q   = (const float*)d_in[0];
    const float* K   = (const float*)d_in[1];
    const float* V   = (const float*)d_in[2];
    const float* pek = (const float*)d_in[3];
    const float* pev = (const float*)d_in[4];
    float* out  = (float*)d_out;
    float* pbuf = out + (size_t)64 * Sc * Dc;   // p_attn follows output

    dim3 grid(8, 64);   // paired q-tiles (b, 15-b): uniform work per block
    relattn<<<grid, 256, 0, stream>>>(Q, K, V, pek, pev, out, pbuf);
}

// Round 11
// 387.034 us; speedup vs baseline: 1.0630x; 1.0630x over previous
//
#include <hip/hip_runtime.h>
#include <math.h>

typedef __attribute__((ext_vector_type(8))) short bfrag;
typedef __attribute__((ext_vector_type(4))) float ffrag;

namespace {
constexpr int Sc = 1024, Dc = 64;
constexpr int P2 = 72;          // bf16 LDS pitch (144 B) for MFMA-read tiles
constexpr int PQ = 64;          // Qs pitch — hoist read is one-time, no pad needed
constexpr int PW = 33;          // f32 pitch for Ts/Ws — bank-spread for row reads
constexpr float S2 = 0.125f * 1.44269504088896f; // SCALE * log2(e)
}

__device__ __forceinline__ unsigned short f2bf(float f) {
    unsigned u = __builtin_bit_cast(unsigned, f);
    u += 0x7fffu + ((u >> 16) & 1u);
    return (unsigned short)(u >> 16);
}
__device__ __forceinline__ bfrag pack8(float4 a, float4 b) {
    bfrag r;
    r[0] = (short)f2bf(a.x); r[1] = (short)f2bf(a.y);
    r[2] = (short)f2bf(a.z); r[3] = (short)f2bf(a.w);
    r[4] = (short)f2bf(b.x); r[5] = (short)f2bf(b.y);
    r[6] = (short)f2bf(b.z); r[7] = (short)f2bf(b.w);
    return r;
}
#define MFMA(a, b, c) __builtin_amdgcn_mfma_f32_16x16x32_bf16((a), (b), (c), 0, 0, 0)

// Pass 1 BATCHED: 3 K-tiles per barrier-window using all six 9KB LDS buffers
// as a slot ring (tile j -> slot j%6). Each window: QK+exp for 3 tiles (12
// independent MFMA chains), pack prefetched next-3, issue loads for next-next-3,
// ONE barrier. 17 windows -> ~6. Staging keeps the coalesced sr/sc4 pattern
// (R10's per-lane global frags were uncoalesced -> reverted).
// Pass 2 unchanged from R9: pipelined QK(kt) || PV(kt-1)+dump, 1 barrier/kt.
__global__ __launch_bounds__(256, 2)
void relattn(const float* __restrict__ Qg, const float* __restrict__ Kg,
             const float* __restrict__ Vg, const float* __restrict__ pek,
             const float* __restrict__ pev, float* __restrict__ outg,
             float* __restrict__ pbuf)
{
    // LDS arena (72448 B, 2 blocks/CU):
    // Ks0 9216 | Ks1 9216 | Vt0 9216 | Vt1 9216 | Pt0 9216 | Pt1 9216 |
    // Ts 8448 | QsArena 8704 (Qs [64][64] bf16 aliased by Ws [64][33] f32 + W0 [64])
    // Pass-1 slot ring: {Ks0,Ks1,Vt0,Vt1,Pt0,Pt1}; pe_k staged in Pt1 (dead after Ts).
    // Ot (64x68 f32 = 17408 B) aliases Ks0+Ks1 (epilogue only).
    __shared__ __align__(16) char smem[72448];
    unsigned short* Ks0 = (unsigned short*)smem;
    unsigned short* Ks1 = (unsigned short*)(smem + 9216);
    unsigned short* Vt0 = (unsigned short*)(smem + 18432);
    unsigned short* Vt1 = (unsigned short*)(smem + 27648);
    unsigned short* Pt0 = (unsigned short*)(smem + 36864);
    unsigned short* Pt1 = (unsigned short*)(smem + 46080);
    float* Ts = (float*)(smem + 55296);                    // [64][33]
    unsigned short* Qs = (unsigned short*)(smem + 63744);  // [64][64]
    float* Ws = (float*)(smem + 63744);                    // [64][33], aliases Qs
    float* W0 = (float*)(smem + 72192);                    // [64]
    float* Ot = (float*)smem;                              // [64][68], aliases Ks0+Ks1

    const int tid  = threadIdx.x;
    const int bh   = blockIdx.y;
    const int wv   = tid >> 6;
    const int lane = tid & 63;
    const int n    = lane & 15;
    const int quad = lane >> 4;

    const float* Qbh = Qg + (size_t)bh * Sc * Dc;
    const float* Kbh = Kg + (size_t)bh * Sc * Dc;
    const float* Vbh = Vg + (size_t)bh * Sc * Dc;
    float* pbh = pbuf + (size_t)bh * Sc * Sc;
    float* obh = outg + (size_t)bh * Sc * Dc;

    const int sr  = tid >> 2;           // staging row 0..63
    const int sc4 = (tid & 3) * 16;     // staging col (floats)
    const int kp  = tid & 31;           // V-transpose k-pair
    const int vd0 = (tid >> 5) * 8;     // V-transpose d base

    // dump-phase coords: thread owns float4 col c4 of rows {rr, 16+rr, 32+rr, 48+rr}
    const int rr = tid >> 4;            // 0..15
    const int c4 = tid & 15;            // 0..15 (float4 col)

    for (int half = 0; half < 2; ++half) {
        const int qt = half ? (15 - (int)blockIdx.x) : (int)blockIdx.x;
        const int qrow = wv * 16 + quad * 4;   // C-layout row base for this lane

        __syncthreads();   // previous half's epilogue fully done with LDS

        // ---- issue loads for tiles 0..2 (latency hides under Q/pe_k staging) ----
        float4 pka[3], pkb[3], pkc[3], pkd[3];
        #pragma unroll
        for (int t = 0; t < 3; ++t) {
            if (t <= qt) {
                const float* ksrc = Kbh + (size_t)(t * 64 + sr) * Dc + sc4;
                pka[t] = *(const float4*)(ksrc);
                pkb[t] = *(const float4*)(ksrc + 4);
                pkc[t] = *(const float4*)(ksrc + 8);
                pkd[t] = *(const float4*)(ksrc + 12);
            }
        }
        // ---- stage Q tile (fp32 -> bf16) ----
        {
            const float* src = Qbh + (size_t)(qt * 64 + sr) * Dc + sc4;
            float4 a = *(const float4*)(src);
            float4 b = *(const float4*)(src + 4);
            float4 c = *(const float4*)(src + 8);
            float4 d = *(const float4*)(src + 12);
            *(bfrag*)&Qs[sr * PQ + sc4]     = pack8(a, b);
            *(bfrag*)&Qs[sr * PQ + sc4 + 8] = pack8(c, d);
        }
        // ---- stage pe_k (rows 0..32) into Pt1; zero rows 33..47 ----
        for (int i = tid; i < 135; i += 256) {          // zero [33*72, 48*72)
            bfrag z = {};
            *(bfrag*)&Pt1[33 * P2 + i * 8] = z;
        }
        if (tid < 132) {
            int r = tid >> 2, c0 = (tid & 3) * 16;
            const float* src = pek + (size_t)r * Dc + c0;
            float4 a = *(const float4*)(src);
            float4 b = *(const float4*)(src + 4);
            float4 c = *(const float4*)(src + 8);
            float4 d = *(const float4*)(src + 12);
            *(bfrag*)&Pt1[r * P2 + c0]     = pack8(a, b);
            *(bfrag*)&Pt1[r * P2 + c0 + 8] = pack8(c, d);
        }
        __syncthreads();

        // ---- hoist Q A-frags (row = wv*16+n, k = d); Qs dead afterwards ----
        bfrag qa0 = *(bfrag*)&Qs[(wv * 16 + n) * PQ + quad * 8];
        bfrag qa1 = *(bfrag*)&Qs[(wv * 16 + n) * PQ + 32 + quad * 8];

        // ---- Ts = Q . pe_k^T via MFMA (from Pt1); pack tiles 0..2 in parallel ----
        #pragma unroll
        for (int sub = 0; sub < 3; ++sub) {
            bfrag b0 = *(bfrag*)&Pt1[(sub * 16 + n) * P2 + quad * 8];
            bfrag b1 = *(bfrag*)&Pt1[(sub * 16 + n) * P2 + 32 + quad * 8];
            ffrag c = {};
            c = MFMA(qa0, b0, c);
            c = MFMA(qa1, b1, c);
            int j = sub * 16 + n;
            if (j <= 32) {
                #pragma unroll
                for (int reg = 0; reg < 4; ++reg)
                    Ts[(qrow + reg) * PW + j] = c[reg];
            }
        }
        // pack tiles 0..2 -> slots 0..2 (Ks0,Ks1,Vt0) — no conflict with Pt1 reads
        #pragma unroll
        for (int t = 0; t < 3; ++t) {
            if (t <= qt) {
                unsigned short* Bn = t == 0 ? Ks0 : (t == 1 ? Ks1 : Vt0);
                *(bfrag*)&Bn[sr * P2 + sc4]     = pack8(pka[t], pkb[t]);
                *(bfrag*)&Bn[sr * P2 + sc4 + 8] = pack8(pkc[t], pkd[t]);
            }
        }
        // issue loads for tiles 3..5
        #pragma unroll
        for (int t = 0; t < 3; ++t) {
            if (3 + t <= qt) {
                const float* ksrc = Kbh + (size_t)((3 + t) * 64 + sr) * Dc + sc4;
                pka[t] = *(const float4*)(ksrc);
                pkb[t] = *(const float4*)(ksrc + 4);
                pkc[t] = *(const float4*)(ksrc + 8);
                pkd[t] = *(const float4*)(ksrc + 12);
            }
        }
        __syncthreads();   // Ts + tiles 0..2 visible; Qs hoisted -> free; Pt1 free

        float ts2[4];   // pre-scaled for exp2: exp((c+ts0)*SCALE) = exp2(fma(c,S2,ts2))
        #pragma unroll
        for (int reg = 0; reg < 4; ++reg) ts2[reg] = Ts[(qrow + reg) * PW] * S2;

        // ---- zero Ws (aliases Qs; safe after barrier) ----
        for (int idx = tid; idx < 64 * PW; idx += 256) Ws[idx] = 0.f;

        // ---- zero-fill fully-masked p region (cols >= (qt+1)*64) ----
        {
            const int zb = (qt + 1) * 64;
            if (zb < Sc) {
                const int z4 = (Sc - zb) >> 2;
                const float4 z = make_float4(0.f, 0.f, 0.f, 0.f);
                for (int r = 0; r < 64; ++r) {
                    float4* rp = (float4*)(pbh + (size_t)(qt * 64 + r) * Sc + zb);
                    for (int cz = tid; cz < z4; cz += 256) rp[cz] = z;
                }
            }
        }

        // ===== pass 1: l = sum(exp(s)) — 3 tiles per barrier-window =====
        float lsum[4] = {0.f, 0.f, 0.f, 0.f};
        for (int kt = 0; kt <= qt; kt += 3) {
            const int ph = (kt / 3) & 1;   // tile j lives in slot j%6
            unsigned short* Bc0 = ph ? Vt1 : Ks0;
            unsigned short* Bc1 = ph ? Pt0 : Ks1;
            unsigned short* Bc2 = ph ? Pt1 : Vt0;
            unsigned short* Bn0 = ph ? Ks0 : Vt1;
            unsigned short* Bn1 = ph ? Ks1 : Pt0;
            unsigned short* Bn2 = ph ? Vt0 : Pt1;

            // ---- compute QK+exp for tiles kt..kt+2 ----
            #pragma unroll
            for (int t = 0; t < 3; ++t) {
                if (kt + t <= qt) {
                    unsigned short* Bc = t == 0 ? Bc0 : (t == 1 ? Bc1 : Bc2);
                    const bool bnd = (kt + t >= qt - 1);
                    #pragma unroll
                    for (int sub = 0; sub < 4; ++sub) {
                        bfrag b0 = *(bfrag*)&Bc[(sub * 16 + n) * P2 + quad * 8];
                        bfrag b1 = *(bfrag*)&Bc[(sub * 16 + n) * P2 + 32 + quad * 8];
                        ffrag c = {};
                        c = MFMA(qa0, b0, c);
                        c = MFMA(qa1, b1, c);
                        const int k = (kt + t) * 64 + sub * 16 + n;
                        if (!bnd) {
                            #pragma unroll
                            for (int reg = 0; reg < 4; ++reg)
                                lsum[reg] += exp2f(fmaf(c[reg], S2, ts2[reg]));
                        } else {
                            #pragma unroll
                            for (int reg = 0; reg < 4; ++reg) {
                                int jrel = k - (qt * 64 + qrow + reg) + 32;
                                if (jrel <= 32) {
                                    int jcl = jrel < 0 ? 0 : jrel;
                                    lsum[reg] += exp2f(fmaf(c[reg] + Ts[(qrow + reg) * PW + jcl], S2, 0.f));
                                }
                            }
                        }
                    }
                }
            }
            // ---- pack prefetched tiles kt+3..kt+5 into next slots ----
            #pragma unroll
            for (int t = 0; t < 3; ++t) {
                if (kt + 3 + t <= qt) {
                    unsigned short* Bn = t == 0 ? Bn0 : (t == 1 ? Bn1 : Bn2);
                    *(bfrag*)&Bn[sr * P2 + sc4]     = pack8(pka[t], pkb[t]);
                    *(bfrag*)&Bn[sr * P2 + sc4 + 8] = pack8(pkc[t], pkd[t]);
                }
            }
            // ---- issue loads for tiles kt+6..kt+8 ----
            #pragma unroll
            for (int t = 0; t < 3; ++t) {
                if (kt + 6 + t <= qt) {
                    const float* ksrc = Kbh + (size_t)((kt + 6 + t) * 64 + sr) * Dc + sc4;
                    pka[t] = *(const float4*)(ksrc);
                    pkb[t] = *(const float4*)(ksrc + 4);
                    pkc[t] = *(const float4*)(ksrc + 8);
                    pkd[t] = *(const float4*)(ksrc + 12);
                }
            }
            __syncthreads();   // window boundary
        }
        float rinv[4];
        #pragma unroll
        for (int reg = 0; reg < 4; ++reg) {
            float l = lsum[reg];
            l += __shfl_xor(l, 1);
            l += __shfl_xor(l, 2);
            l += __shfl_xor(l, 4);
            l += __shfl_xor(l, 8);
            rinv[reg] = 1.f / l;
        }

        // ---- pass-2 prologue: restage K[0]->Ks0 (L2-hot); issue K[1], V[0] ----
        {
            const float* ksrc = Kbh + (size_t)sr * Dc + sc4;
            float4 a = *(const float4*)(ksrc);
            float4 b = *(const float4*)(ksrc + 4);
            float4 c = *(const float4*)(ksrc + 8);
            float4 d = *(const float4*)(ksrc + 12);
            *(bfrag*)&Ks0[sr * P2 + sc4]     = pack8(a, b);
            *(bfrag*)&Ks0[sr * P2 + sc4 + 8] = pack8(c, d);
        }
        if (qt >= 1) {
            const float* ksrc = Kbh + (size_t)(64 + sr) * Dc + sc4;
            pka[0] = *(const float4*)(ksrc);
            pkb[0] = *(const float4*)(ksrc + 4);
            pkc[0] = *(const float4*)(ksrc + 8);
            pkd[0] = *(const float4*)(ksrc + 12);
        }
        float4 pva, pvb, pvc, pvd;
        {
            const float* vsrc = Vbh + (size_t)(2 * kp) * Dc + vd0;
            pva = *(const float4*)(vsrc);
            pvb = *(const float4*)(vsrc + 4);
            pvc = *(const float4*)(vsrc + Dc);
            pvd = *(const float4*)(vsrc + Dc + 4);
        }
        __syncthreads();   // K[0] visible; pass-1 slot reads done

        // ====== pass 2 (pipelined, 1 barrier/kt): QK(kt) || PV(kt-1)+dump ======
        ffrag oacc[4];
        #pragma unroll
        for (int i = 0; i < 4; ++i) { ffrag z = {}; oacc[i] = z; }

        for (int kt = 0; kt <= qt; ++kt) {
            const bool bnd = (kt >= qt - 1);
            unsigned short* Kc  = (kt & 1) ? Ks1 : Ks0;   // K[kt] (K[0] in Ks0)
            unsigned short* Kn  = (kt & 1) ? Ks0 : Ks1;
            unsigned short* Vc  = (kt & 1) ? Vt1 : Vt0;   // stage target for V[kt]
            unsigned short* Vp  = (kt & 1) ? Vt0 : Vt1;   // V[kt-1] for PV
            unsigned short* Ptc = (kt & 1) ? Pt1 : Pt0;   // QK(kt) writes
            unsigned short* Ptp = (kt & 1) ? Pt0 : Pt1;   // PV(kt-1) reads

            // ---- QK(kt): scores -> Ptc (bf16, normalized), rel-v capture ----
            #pragma unroll
            for (int sub = 0; sub < 4; ++sub) {
                bfrag b0 = *(bfrag*)&Kc[(sub * 16 + n) * P2 + quad * 8];
                bfrag b1 = *(bfrag*)&Kc[(sub * 16 + n) * P2 + 32 + quad * 8];
                ffrag c = {};
                c = MFMA(qa0, b0, c);
                c = MFMA(qa1, b1, c);
                const int k = kt * 64 + sub * 16 + n;
                if (!bnd) {
                    #pragma unroll
                    for (int reg = 0; reg < 4; ++reg) {
                        float p = exp2f(fmaf(c[reg], S2, ts2[reg])) * rinv[reg];
                        Ptc[(qrow + reg) * P2 + sub * 16 + n] = (unsigned short)f2bf(p);
                    }
                } else {
                    #pragma unroll
                    for (int reg = 0; reg < 4; ++reg) {
                        int jrel = k - (qt * 64 + qrow + reg) + 32;
                        float p = 0.f;
                        if (jrel <= 32) {
                            int jcl = jrel < 0 ? 0 : jrel;
                            p = exp2f((c[reg] + Ts[(qrow + reg) * PW + jcl]) * S2) * rinv[reg];
                        }
                        Ptc[(qrow + reg) * P2 + sub * 16 + n] = (unsigned short)f2bf(p);
                        if ((unsigned)(jrel - 1) < 32u) Ws[(qrow + reg) * PW + jrel - 1] = p;
                    }
                }
            }
            // ---- stage K[kt+1] -> Kn; V[kt] -> Vc (regs from last window) ----
            if (kt < qt) {
                *(bfrag*)&Kn[sr * P2 + sc4]     = pack8(pka[0], pkb[0]);
                *(bfrag*)&Kn[sr * P2 + sc4 + 8] = pack8(pkc[0], pkd[0]);
            }
            {
                float r0[8] = {pva.x, pva.y, pva.z, pva.w, pvb.x, pvb.y, pvb.z, pvb.w};
                float r1[8] = {pvc.x, pvc.y, pvc.z, pvc.w, pvd.x, pvd.y, pvd.z, pvd.w};
                #pragma unroll
                for (int i = 0; i < 8; ++i) {
                    unsigned pk2 = (unsigned)f2bf(r0[i]) | ((unsigned)f2bf(r1[i]) << 16);
                    *(unsigned*)&Vc[(vd0 + i) * P2 + 2 * kp] = pk2;   // Vc[d][k]
                }
            }
            // ---- issue next prefetches ----
            if (kt + 2 <= qt) {
                const float* ksrc = Kbh + (size_t)((kt + 2) * 64 + sr) * Dc + sc4;
                pka[0] = *(const float4*)(ksrc);
                pkb[0] = *(const float4*)(ksrc + 4);
                pkc[0] = *(const float4*)(ksrc + 8);
                pkd[0] = *(const float4*)(ksrc + 12);
            }
            if (kt + 1 <= qt) {
                const float* vsrc = Vbh + (size_t)((kt + 1) * 64 + 2 * kp) * Dc + vd0;
                pva = *(const float4*)(vsrc);
                pvb = *(const float4*)(vsrc + 4);
                pvc = *(const float4*)(vsrc + Dc);
                pvd = *(const float4*)(vsrc + Dc + 4);
            }
            // ---- PV(kt-1) + dump(kt-1): independent of QK(kt) ----
            if (kt >= 1) {
                bfrag pb0 = *(bfrag*)&Ptp[(wv * 16 + n) * P2 + quad * 8];
                bfrag pb1 = *(bfrag*)&Ptp[(wv * 16 + n) * P2 + 32 + quad * 8];
                #pragma unroll
                for (int ds = 0; ds < 4; ++ds) {
                    bfrag va0 = *(bfrag*)&Vp[(ds * 16 + n) * P2 + quad * 8];
                    bfrag va1 = *(bfrag*)&Vp[(ds * 16 + n) * P2 + 32 + quad * 8];
                    oacc[ds] = MFMA(va0, pb0, oacc[ds]);
                    oacc[ds] = MFMA(va1, pb1, oacc[ds]);
                }
                float* base = pbh + ((size_t)(qt * 64 + rr) * Sc + (kt - 1) * 64 + c4 * 4);
                #pragma unroll
                for (int step = 0; step < 4; ++step) {
                    const int r = step * 16 + rr;
                    uint2 two = *(const uint2*)&Ptp[r * P2 + c4 * 4];   // ds_read_b64
                    float4 v;
                    v.x = __builtin_bit_cast(float, (two.x & 0xffffu) << 16);
                    v.y = __builtin_bit_cast(float, two.x & 0xffff0000u);
                    v.z = __builtin_bit_cast(float, (two.y & 0xffffu) << 16);
                    v.w = __builtin_bit_cast(float, two.y & 0xffff0000u);
                    *(float4*)(base + (size_t)(step * 16) * Sc) = v;
                }
            }
            __syncthreads();   // window boundary
        }
        // ---- drain: PV(qt) + dump(qt) ----
        {
            unsigned short* Ptp = (qt & 1) ? Pt1 : Pt0;
            unsigned short* Vp  = (qt & 1) ? Vt1 : Vt0;
            bfrag pb0 = *(bfrag*)&Ptp[(wv * 16 + n) * P2 + quad * 8];
            bfrag pb1 = *(bfrag*)&Ptp[(wv * 16 + n) * P2 + 32 + quad * 8];
            #pragma unroll
            for (int ds = 0; ds < 4; ++ds) {
                bfrag va0 = *(bfrag*)&Vp[(ds * 16 + n) * P2 + quad * 8];
                bfrag va1 = *(bfrag*)&Vp[(ds * 16 + n) * P2 + 32 + quad * 8];
                oacc[ds] = MFMA(va0, pb0, oacc[ds]);
                oacc[ds] = MFMA(va1, pb1, oacc[ds]);
            }
            float* base = pbh + ((size_t)(qt * 64 + rr) * Sc + qt * 64 + c4 * 4);
            #pragma unroll
            for (int step = 0; step < 4; ++step) {
                const int r = step * 16 + rr;
                uint2 two = *(const uint2*)&Ptp[r * P2 + c4 * 4];   // ds_read_b64
                float4 v;
                v.x = __builtin_bit_cast(float, (two.x & 0xffffu) << 16);
                v.y = __builtin_bit_cast(float, two.x & 0xffff0000u);
                v.z = __builtin_bit_cast(float, (two.y & 0xffffu) << 16);
                v.w = __builtin_bit_cast(float, two.y & 0xffff0000u);
                *(float4*)(base + (size_t)(step * 16) * Sc) = v;
            }
        }
        __syncthreads();   // all PV/dump reads done before epilogue prep writes

        // ================= epilogue: rel-v term + store O =================
        if (tid < 64) {
            float s = 0.f;
            #pragma unroll
            for (int j = 0; j < 32; ++j) s += Ws[tid * PW + j];   // pitch-33: conflict-free
            W0[tid] = 1.f - s;   // mass of far past (jrel<=0)
        }
        {   // Pt0[q][jj] <- Ws (bf16), jj = jrel-1 in 0..31
            int q = tid >> 2, j0 = (tid & 3) * 8;
            #pragma unroll
            for (int i = 0; i < 8; i += 2) {
                unsigned pk2 = (unsigned)f2bf(Ws[q * PW + j0 + i]) |
                               ((unsigned)f2bf(Ws[q * PW + j0 + i + 1]) << 16);
                *(unsigned*)&Pt0[q * P2 + j0 + i] = pk2;
            }
        }
        {   // Vt0[d][jj] <- pe_v[jj+1][d]
            int jj = tid >> 3, d0 = (tid & 7) * 8;
            const float* src = pev + (size_t)(jj + 1) * Dc + d0;
            float4 a = *(const float4*)(src);
            float4 b = *(const float4*)(src + 4);
            float vr[8] = {a.x, a.y, a.z, a.w, b.x, b.y, b.z, b.w};
            #pragma unroll
            for (int i = 0; i < 8; ++i)
                Vt0[(d0 + i) * P2 + jj] = (unsigned short)f2bf(vr[i]);
        }
        __syncthreads();   // Pt0/Vt0/W0 prep visible
        {
            bfrag pb = *(bfrag*)&Pt0[(wv * 16 + n) * P2 + quad * 8];
            #pragma unroll
            for (int ds = 0; ds < 4; ++ds) {
                bfrag va = *(bfrag*)&Vt0[(ds * 16 + n) * P2 + quad * 8];
                oacc[ds] = MFMA(va, pb, oacc[ds]);
            }
        }
        float w0q = W0[wv * 16 + n];
        // Ot aliases Ks0/Ks1 only (dead) — no barrier needed before write
        #pragma unroll
        for (int ds = 0; ds < 4; ++ds) {
            float4 ov;
            ov.x = oacc[ds][0] + w0q * pev[ds * 16 + quad * 4 + 0];
            ov.y = oacc[ds][1] + w0q * pev[ds * 16 + quad * 4 + 1];
            ov.z = oacc[ds][2] + w0q * pev[ds * 16 + quad * 4 + 2];
            ov.w = oacc[ds][3] + w0q * pev[ds * 16 + quad * 4 + 3];
            *(float4*)&Ot[(wv * 16 + n) * 68 + ds * 16 + quad * 4] = ov;
        }
        __syncthreads();
        {
            int r = tid >> 2, c0 = (tid & 3) * 16;
            float* dst = obh + (size_t)(qt * 64 + r) * Dc + c0;
            *(float4*)(dst)      = *(float4*)&Ot[r * 68 + c0];
            *(float4*)(dst + 4)  = *(float4*)&Ot[r * 68 + c0 + 4];
            *(float4*)(dst + 8)  = *(float4*)&Ot[r * 68 + c0 + 8];
            *(float4*)(dst + 12) = *(float4*)&Ot[r * 68 + c0 + 12];
        }
    }
}

extern "C" void kernel_launch(void* const* d_in, const int* in_sizes, int n_in,
                              void* d_out, int out_size, void* d_ws, size_t ws_size,
                              hipStream_t stream)
{
    const float* Q   = (const float*)d_in[0];
    const float* K   = (const float*)d_in[1];
    const float* V   = (const float*)d_in[2];
    const float* pek = (const float*)d_in[3];
    const float* pev = (const float*)d_in[4];
    float* out  = (float*)d_out;
    float* pbuf = out + (size_t)64 * Sc * Dc;   // p_attn follows output

    dim3 grid(8, 64);   // paired q-tiles (b, 15-b): uniform work per block
    relattn<<<grid, 256, 0, stream>>>(Q, K, V, pek, pev, out, pbuf);
}

// Round 12
// 377.693 us; speedup vs baseline: 1.0893x; 1.0247x over previous
//
#include <hip/hip_runtime.h>
#include <math.h>

typedef __attribute__((ext_vector_type(8))) short bfrag;
typedef __attribute__((ext_vector_type(4))) float ffrag;

namespace {
constexpr int Sc = 1024, Dc = 64;
constexpr int P2 = 72;          // bf16 LDS pitch (144 B) for MFMA-read tiles
constexpr int PQ = 64;          // Qs pitch — hoist read is one-time, no pad needed
constexpr int PW = 33;          // f32 pitch for Ts/Ws — bank-spread for row reads
constexpr float S2 = 0.125f * 1.44269504088896f; // SCALE * log2(e)
}

__device__ __forceinline__ unsigned short f2bf(float f) {
    unsigned u = __builtin_bit_cast(unsigned, f);
    u += 0x7fffu + ((u >> 16) & 1u);
    return (unsigned short)(u >> 16);
}
__device__ __forceinline__ bfrag pack8(float4 a, float4 b) {
    bfrag r;
    r[0] = (short)f2bf(a.x); r[1] = (short)f2bf(a.y);
    r[2] = (short)f2bf(a.z); r[3] = (short)f2bf(a.w);
    r[4] = (short)f2bf(b.x); r[5] = (short)f2bf(b.y);
    r[6] = (short)f2bf(b.z); r[7] = (short)f2bf(b.w);
    return r;
}
__device__ __forceinline__ float bfu(unsigned u) {
    return __builtin_bit_cast(float, u);
}
#define MFMA(a, b, c) __builtin_amdgcn_mfma_f32_16x16x32_bf16((a), (b), (c), 0, 0, 0)

// Best-known structure (R9): paired q-tiles (512 blocks, balanced); pass 2
// software-pipelined to ONE barrier per kt: window kt = { QK(kt) -> Pt[kt&1] |
// stage K[kt+1],V[kt] | PV(kt-1)+dump(kt-1) }. exp via exp2f(fma). Micros this
// rev: Ws zeroing via float4 (3 LDS writes, was 9) and dump Pt reads via b128
// (2 LDS reads/kt, was 4) — identical coverage, 16B-aligned.
__global__ __launch_bounds__(256, 2)
void relattn(const float* __restrict__ Qg, const float* __restrict__ Kg,
             const float* __restrict__ Vg, const float* __restrict__ pek,
             const float* __restrict__ pev, float* __restrict__ outg,
             float* __restrict__ pbuf)
{
    // LDS arena (72448 B, 2 blocks/CU):
    // Ks0 9216 | Ks1 9216 | Vt0 9216 | Vt1 9216 | Pt0 9216 | Pt1 9216 |
    // Ts 8448 | QsArena 8704 (Qs [64][64] bf16 aliased by Ws [64][33] f32 + W0 [64])
    // Ot (64x68 f32 = 17408 B) aliases Ks0+Ks1 (epilogue only).
    __shared__ __align__(16) char smem[72448];
    unsigned short* Ks0 = (unsigned short*)smem;
    unsigned short* Ks1 = (unsigned short*)(smem + 9216);
    unsigned short* Vt0 = (unsigned short*)(smem + 18432);
    unsigned short* Vt1 = (unsigned short*)(smem + 27648);
    unsigned short* Pt0 = (unsigned short*)(smem + 36864);
    unsigned short* Pt1 = (unsigned short*)(smem + 46080);
    float* Ts = (float*)(smem + 55296);                    // [64][33]
    unsigned short* Qs = (unsigned short*)(smem + 63744);  // [64][64]
    float* Ws = (float*)(smem + 63744);                    // [64][33], aliases Qs
    float* W0 = (float*)(smem + 72192);                    // [64]
    float* Ot = (float*)smem;                              // [64][68], aliases Ks0+Ks1

    const int tid  = threadIdx.x;
    const int bh   = blockIdx.y;
    const int wv   = tid >> 6;
    const int lane = tid & 63;
    const int n    = lane & 15;
    const int quad = lane >> 4;

    const float* Qbh = Qg + (size_t)bh * Sc * Dc;
    const float* Kbh = Kg + (size_t)bh * Sc * Dc;
    const float* Vbh = Vg + (size_t)bh * Sc * Dc;
    float* pbh = pbuf + (size_t)bh * Sc * Sc;
    float* obh = outg + (size_t)bh * Sc * Dc;

    const int sr  = tid >> 2;           // staging row 0..63
    const int sc4 = (tid & 3) * 16;     // staging col (floats)
    const int kp  = tid & 31;           // V-transpose k-pair
    const int vd0 = (tid >> 5) * 8;     // V-transpose d base

    // dump-phase coords: thread owns 8-float col group c8 of rows {rr2, 32+rr2}
    const int rr2 = tid >> 3;           // 0..31
    const int c8  = tid & 7;            // 0..7

    for (int half = 0; half < 2; ++half) {
        const int qt = half ? (15 - (int)blockIdx.x) : (int)blockIdx.x;
        const int qrow = wv * 16 + quad * 4;   // C-layout row base for this lane

        __syncthreads();   // previous half's epilogue fully done with LDS

        // ---- issue K[0] loads first (latency hides under Q/pe_k staging + Ts) ----
        float4 k0a, k0b, k0c, k0d;
        {
            const float* ksrc = Kbh + (size_t)sr * Dc + sc4;
            k0a = *(const float4*)(ksrc);
            k0b = *(const float4*)(ksrc + 4);
            k0c = *(const float4*)(ksrc + 8);
            k0d = *(const float4*)(ksrc + 12);
        }
        // ---- stage Q tile (fp32 -> bf16) ----
        {
            const float* src = Qbh + (size_t)(qt * 64 + sr) * Dc + sc4;
            float4 a = *(const float4*)(src);
            float4 b = *(const float4*)(src + 4);
            float4 c = *(const float4*)(src + 8);
            float4 d = *(const float4*)(src + 12);
            *(bfrag*)&Qs[sr * PQ + sc4]     = pack8(a, b);
            *(bfrag*)&Qs[sr * PQ + sc4 + 8] = pack8(c, d);
        }
        // ---- stage pe_k (rows 0..32) into Ks0; zero rows 33..47 ----
        for (int i = tid; i < 135; i += 256) {          // zero [33*72, 48*72)
            bfrag z = {};
            *(bfrag*)&Ks0[33 * P2 + i * 8] = z;
        }
        if (tid < 132) {
            int r = tid >> 2, c0 = (tid & 3) * 16;
            const float* src = pek + (size_t)r * Dc + c0;
            float4 a = *(const float4*)(src);
            float4 b = *(const float4*)(src + 4);
            float4 c = *(const float4*)(src + 8);
            float4 d = *(const float4*)(src + 12);
            *(bfrag*)&Ks0[r * P2 + c0]     = pack8(a, b);
            *(bfrag*)&Ks0[r * P2 + c0 + 8] = pack8(c, d);
        }
        __syncthreads();

        // ---- hoist Q A-frags (row = wv*16+n, k = d); Qs dead afterwards ----
        bfrag qa0 = *(bfrag*)&Qs[(wv * 16 + n) * PQ + quad * 8];
        bfrag qa1 = *(bfrag*)&Qs[(wv * 16 + n) * PQ + 32 + quad * 8];

        // ---- Ts = Q . pe_k^T via MFMA (j in 0..47, keep j<=32) ----
        #pragma unroll
        for (int sub = 0; sub < 3; ++sub) {
            bfrag b0 = *(bfrag*)&Ks0[(sub * 16 + n) * P2 + quad * 8];
            bfrag b1 = *(bfrag*)&Ks0[(sub * 16 + n) * P2 + 32 + quad * 8];
            ffrag c = {};
            c = MFMA(qa0, b0, c);
            c = MFMA(qa1, b1, c);
            int j = sub * 16 + n;
            if (j <= 32) {
                #pragma unroll
                for (int reg = 0; reg < 4; ++reg)
                    Ts[(qrow + reg) * PW + j] = c[reg];
            }
        }
        // ---- pack K[0] -> Ks1 (waits k0*); issue K[1] prefetch ----
        *(bfrag*)&Ks1[sr * P2 + sc4]     = pack8(k0a, k0b);
        *(bfrag*)&Ks1[sr * P2 + sc4 + 8] = pack8(k0c, k0d);
        float4 pka, pkb, pkc, pkd;
        if (qt >= 1) {
            const float* ksrc = Kbh + (size_t)(64 + sr) * Dc + sc4;
            pka = *(const float4*)(ksrc);
            pkb = *(const float4*)(ksrc + 4);
            pkc = *(const float4*)(ksrc + 8);
            pkd = *(const float4*)(ksrc + 12);
        }
        __syncthreads();   // Ts + K[0] visible; all waves hoisted Q -> Qs free

        float ts2[4];   // pre-scaled for exp2: exp((c+ts0)*SCALE) = exp2(fma(c,S2,ts2))
        #pragma unroll
        for (int reg = 0; reg < 4; ++reg) ts2[reg] = Ts[(qrow + reg) * PW] * S2;

        // ---- zero Ws (aliases Qs; safe after barrier) — float4 writes ----
        {
            float4* w4 = (float4*)Ws;
            const float4 z = make_float4(0.f, 0.f, 0.f, 0.f);
            for (int i = tid; i < (64 * PW) / 4; i += 256) w4[i] = z;
        }

        // ---- zero-fill fully-masked p region (cols >= (qt+1)*64) ----
        {
            const int zb = (qt + 1) * 64;
            if (zb < Sc) {
                const int z4 = (Sc - zb) >> 2;
                const float4 z = make_float4(0.f, 0.f, 0.f, 0.f);
                for (int r = 0; r < 64; ++r) {
                    float4* rp = (float4*)(pbh + (size_t)(qt * 64 + r) * Sc + zb);
                    for (int cz = tid; cz < z4; cz += 256) rp[cz] = z;
                }
            }
        }

        // ================= pass 1: l = sum(exp(s)), 1 barrier/kt =================
        float lsum[4] = {0.f, 0.f, 0.f, 0.f};
        for (int kt = 0; kt <= qt; ++kt) {
            const bool bnd = (kt >= qt - 1);
            unsigned short* Kc = (kt & 1) ? Ks0 : Ks1;   // K[0] lives in Ks1
            unsigned short* Kn = (kt & 1) ? Ks1 : Ks0;
            #pragma unroll
            for (int sub = 0; sub < 4; ++sub) {
                bfrag b0 = *(bfrag*)&Kc[(sub * 16 + n) * P2 + quad * 8];
                bfrag b1 = *(bfrag*)&Kc[(sub * 16 + n) * P2 + 32 + quad * 8];
                ffrag c = {};
                c = MFMA(qa0, b0, c);
                c = MFMA(qa1, b1, c);
                const int k = kt * 64 + sub * 16 + n;
                if (!bnd) {
                    #pragma unroll
                    for (int reg = 0; reg < 4; ++reg)
                        lsum[reg] += exp2f(fmaf(c[reg], S2, ts2[reg]));
                } else {
                    #pragma unroll
                    for (int reg = 0; reg < 4; ++reg) {
                        int jrel = k - (qt * 64 + qrow + reg) + 32;
                        if (jrel <= 32) {
                            int jcl = jrel < 0 ? 0 : jrel;
                            lsum[reg] += exp2f(fmaf(c[reg] + Ts[(qrow + reg) * PW + jcl], S2, 0.f));
                        }
                    }
                }
            }
            if (kt < qt) {     // stage K[kt+1] (regs prefetched last iter)
                *(bfrag*)&Kn[sr * P2 + sc4]     = pack8(pka, pkb);
                *(bfrag*)&Kn[sr * P2 + sc4 + 8] = pack8(pkc, pkd);
            }
            if (kt + 2 <= qt) {   // issue K[kt+2]
                const float* ksrc = Kbh + (size_t)((kt + 2) * 64 + sr) * Dc + sc4;
                pka = *(const float4*)(ksrc);
                pkb = *(const float4*)(ksrc + 4);
                pkc = *(const float4*)(ksrc + 8);
                pkd = *(const float4*)(ksrc + 12);
            }
            __syncthreads();
        }
        float rinv[4];
        #pragma unroll
        for (int reg = 0; reg < 4; ++reg) {
            float l = lsum[reg];
            l += __shfl_xor(l, 1);
            l += __shfl_xor(l, 2);
            l += __shfl_xor(l, 4);
            l += __shfl_xor(l, 8);
            rinv[reg] = 1.f / l;
        }

        // ---- pass-2 prologue: restage K[0]->Ks0 (L2-hot); issue K[1], V[0] ----
        {
            const float* ksrc = Kbh + (size_t)sr * Dc + sc4;
            float4 a = *(const float4*)(ksrc);
            float4 b = *(const float4*)(ksrc + 4);
            float4 c = *(const float4*)(ksrc + 8);
            float4 d = *(const float4*)(ksrc + 12);
            *(bfrag*)&Ks0[sr * P2 + sc4]     = pack8(a, b);
            *(bfrag*)&Ks0[sr * P2 + sc4 + 8] = pack8(c, d);
        }
        if (qt >= 1) {
            const float* ksrc = Kbh + (size_t)(64 + sr) * Dc + sc4;
            pka = *(const float4*)(ksrc);
            pkb = *(const float4*)(ksrc + 4);
            pkc = *(const float4*)(ksrc + 8);
            pkd = *(const float4*)(ksrc + 12);
        }
        float4 pva, pvb, pvc, pvd;
        {
            const float* vsrc = Vbh + (size_t)(2 * kp) * Dc + vd0;
            pva = *(const float4*)(vsrc);
            pvb = *(const float4*)(vsrc + 4);
            pvc = *(const float4*)(vsrc + Dc);
            pvd = *(const float4*)(vsrc + Dc + 4);
        }
        __syncthreads();   // K[0] visible

        // ====== pass 2 (pipelined, 1 barrier/kt): QK(kt) || PV(kt-1)+dump ======
        ffrag oacc[4];
        #pragma unroll
        for (int i = 0; i < 4; ++i) { ffrag z = {}; oacc[i] = z; }

        for (int kt = 0; kt <= qt; ++kt) {
            const bool bnd = (kt >= qt - 1);
            unsigned short* Kc  = (kt & 1) ? Ks1 : Ks0;   // K[kt] (K[0] in Ks0)
            unsigned short* Kn  = (kt & 1) ? Ks0 : Ks1;
            unsigned short* Vc  = (kt & 1) ? Vt1 : Vt0;   // stage target for V[kt]
            unsigned short* Vp  = (kt & 1) ? Vt0 : Vt1;   // V[kt-1] for PV
            unsigned short* Ptc = (kt & 1) ? Pt1 : Pt0;   // QK(kt) writes
            unsigned short* Ptp = (kt & 1) ? Pt0 : Pt1;   // PV(kt-1) reads

            // ---- QK(kt): scores -> Ptc (bf16, normalized), rel-v capture ----
            #pragma unroll
            for (int sub = 0; sub < 4; ++sub) {
                bfrag b0 = *(bfrag*)&Kc[(sub * 16 + n) * P2 + quad * 8];
                bfrag b1 = *(bfrag*)&Kc[(sub * 16 + n) * P2 + 32 + quad * 8];
                ffrag c = {};
                c = MFMA(qa0, b0, c);
                c = MFMA(qa1, b1, c);
                const int k = kt * 64 + sub * 16 + n;
                if (!bnd) {
                    #pragma unroll
                    for (int reg = 0; reg < 4; ++reg) {
                        float p = exp2f(fmaf(c[reg], S2, ts2[reg])) * rinv[reg];
                        Ptc[(qrow + reg) * P2 + sub * 16 + n] = (unsigned short)f2bf(p);
                    }
                } else {
                    #pragma unroll
                    for (int reg = 0; reg < 4; ++reg) {
                        int jrel = k - (qt * 64 + qrow + reg) + 32;
                        float p = 0.f;
                        if (jrel <= 32) {
                            int jcl = jrel < 0 ? 0 : jrel;
                            p = exp2f((c[reg] + Ts[(qrow + reg) * PW + jcl]) * S2) * rinv[reg];
                        }
                        Ptc[(qrow + reg) * P2 + sub * 16 + n] = (unsigned short)f2bf(p);
                        if ((unsigned)(jrel - 1) < 32u) Ws[(qrow + reg) * PW + jrel - 1] = p;
                    }
                }
            }
            // ---- stage K[kt+1] -> Kn; V[kt] -> Vc (regs from last window) ----
            if (kt < qt) {
                *(bfrag*)&Kn[sr * P2 + sc4]     = pack8(pka, pkb);
                *(bfrag*)&Kn[sr * P2 + sc4 + 8] = pack8(pkc, pkd);
            }
            {
                float r0[8] = {pva.x, pva.y, pva.z, pva.w, pvb.x, pvb.y, pvb.z, pvb.w};
                float r1[8] = {pvc.x, pvc.y, pvc.z, pvc.w, pvd.x, pvd.y, pvd.z, pvd.w};
                #pragma unroll
                for (int i = 0; i < 8; ++i) {
                    unsigned pk2 = (unsigned)f2bf(r0[i]) | ((unsigned)f2bf(r1[i]) << 16);
                    *(unsigned*)&Vc[(vd0 + i) * P2 + 2 * kp] = pk2;   // Vc[d][k]
                }
            }
            // ---- issue next prefetches ----
            if (kt + 2 <= qt) {
                const float* ksrc = Kbh + (size_t)((kt + 2) * 64 + sr) * Dc + sc4;
                pka = *(const float4*)(ksrc);
                pkb = *(const float4*)(ksrc + 4);
                pkc = *(const float4*)(ksrc + 8);
                pkd = *(const float4*)(ksrc + 12);
            }
            if (kt + 1 <= qt) {
                const float* vsrc = Vbh + (size_t)((kt + 1) * 64 + 2 * kp) * Dc + vd0;
                pva = *(const float4*)(vsrc);
                pvb = *(const float4*)(vsrc + 4);
                pvc = *(const float4*)(vsrc + Dc);
                pvd = *(const float4*)(vsrc + Dc + 4);
            }
            // ---- PV(kt-1) + dump(kt-1): independent of QK(kt) ----
            if (kt >= 1) {
                bfrag pb0 = *(bfrag*)&Ptp[(wv * 16 + n) * P2 + quad * 8];
                bfrag pb1 = *(bfrag*)&Ptp[(wv * 16 + n) * P2 + 32 + quad * 8];
                #pragma unroll
                for (int ds = 0; ds < 4; ++ds) {
                    bfrag va0 = *(bfrag*)&Vp[(ds * 16 + n) * P2 + quad * 8];
                    bfrag va1 = *(bfrag*)&Vp[(ds * 16 + n) * P2 + 32 + quad * 8];
                    oacc[ds] = MFMA(va0, pb0, oacc[ds]);
                    oacc[ds] = MFMA(va1, pb1, oacc[ds]);
                }
                float* base = pbh + ((size_t)(qt * 64 + rr2) * Sc + (kt - 1) * 64 + c8 * 8);
                #pragma unroll
                for (int step = 0; step < 2; ++step) {
                    const int r = step * 32 + rr2;
                    uint4 four = *(const uint4*)&Ptp[r * P2 + c8 * 8];   // ds_read_b128
                    float4 v0, v1;
                    v0.x = bfu((four.x & 0xffffu) << 16); v0.y = bfu(four.x & 0xffff0000u);
                    v0.z = bfu((four.y & 0xffffu) << 16); v0.w = bfu(four.y & 0xffff0000u);
                    v1.x = bfu((four.z & 0xffffu) << 16); v1.y = bfu(four.z & 0xffff0000u);
                    v1.z = bfu((four.w & 0xffffu) << 16); v1.w = bfu(four.w & 0xffff0000u);
                    float* rp = base + (size_t)(step * 32) * Sc;
                    *(float4*)(rp)     = v0;
                    *(float4*)(rp + 4) = v1;
                }
            }
            __syncthreads();   // window boundary
        }
        // ---- drain: PV(qt) + dump(qt) ----
        {
            unsigned short* Ptp = (qt & 1) ? Pt1 : Pt0;
            unsigned short* Vp  = (qt & 1) ? Vt1 : Vt0;
            bfrag pb0 = *(bfrag*)&Ptp[(wv * 16 + n) * P2 + quad * 8];
            bfrag pb1 = *(bfrag*)&Ptp[(wv * 16 + n) * P2 + 32 + quad * 8];
            #pragma unroll
            for (int ds = 0; ds < 4; ++ds) {
                bfrag va0 = *(bfrag*)&Vp[(ds * 16 + n) * P2 + quad * 8];
                bfrag va1 = *(bfrag*)&Vp[(ds * 16 + n) * P2 + 32 + quad * 8];
                oacc[ds] = MFMA(va0, pb0, oacc[ds]);
                oacc[ds] = MFMA(va1, pb1, oacc[ds]);
            }
            float* base = pbh + ((size_t)(qt * 64 + rr2) * Sc + qt * 64 + c8 * 8);
            #pragma unroll
            for (int step = 0; step < 2; ++step) {
                const int r = step * 32 + rr2;
                uint4 four = *(const uint4*)&Ptp[r * P2 + c8 * 8];   // ds_read_b128
                float4 v0, v1;
                v0.x = bfu((four.x & 0xffffu) << 16); v0.y = bfu(four.x & 0xffff0000u);
                v0.z = bfu((four.y & 0xffffu) << 16); v0.w = bfu(four.y & 0xffff0000u);
                v1.x = bfu((four.z & 0xffffu) << 16); v1.y = bfu(four.z & 0xffff0000u);
                v1.z = bfu((four.w & 0xffffu) << 16); v1.w = bfu(four.w & 0xffff0000u);
                float* rp = base + (size_t)(step * 32) * Sc;
                *(float4*)(rp)     = v0;
                *(float4*)(rp + 4) = v1;
            }
        }
        __syncthreads();   // all PV/dump reads done before epilogue prep writes

        // ================= epilogue: rel-v term + store O =================
        if (tid < 64) {
            float s = 0.f;
            #pragma unroll
            for (int j = 0; j < 32; ++j) s += Ws[tid * PW + j];   // pitch-33: conflict-free
            W0[tid] = 1.f - s;   // mass of far past (jrel<=0)
        }
        {   // Pt0[q][jj] <- Ws (bf16), jj = jrel-1 in 0..31
            int q = tid >> 2, j0 = (tid & 3) * 8;
            #pragma unroll
            for (int i = 0; i < 8; i += 2) {
                unsigned pk2 = (unsigned)f2bf(Ws[q * PW + j0 + i]) |
                               ((unsigned)f2bf(Ws[q * PW + j0 + i + 1]) << 16);
                *(unsigned*)&Pt0[q * P2 + j0 + i] = pk2;
            }
        }
        {   // Vt0[d][jj] <- pe_v[jj+1][d]
            int jj = tid >> 3, d0 = (tid & 7) * 8;
            const float* src = pev + (size_t)(jj + 1) * Dc + d0;
            float4 a = *(const float4*)(src);
            float4 b = *(const float4*)(src + 4);
            float vr[8] = {a.x, a.y, a.z, a.w, b.x, b.y, b.z, b.w};
            #pragma unroll
            for (int i = 0; i < 8; ++i)
                Vt0[(d0 + i) * P2 + jj] = (unsigned short)f2bf(vr[i]);
        }
        __syncthreads();   // Pt0/Vt0/W0 prep visible
        {
            bfrag pb = *(bfrag*)&Pt0[(wv * 16 + n) * P2 + quad * 8];
            #pragma unroll
            for (int ds = 0; ds < 4; ++ds) {
                bfrag va = *(bfrag*)&Vt0[(ds * 16 + n) * P2 + quad * 8];
                oacc[ds] = MFMA(va, pb, oacc[ds]);
            }
        }
        float w0q = W0[wv * 16 + n];
        // Ot aliases Ks0/Ks1 only (dead) — no barrier needed before write
        #pragma unroll
        for (int ds = 0; ds < 4; ++ds) {
            float4 ov;
            ov.x = oacc[ds][0] + w0q * pev[ds * 16 + quad * 4 + 0];
            ov.y = oacc[ds][1] + w0q * pev[ds * 16 + quad * 4 + 1];
            ov.z = oacc[ds][2] + w0q * pev[ds * 16 + quad * 4 + 2];
            ov.w = oacc[ds][3] + w0q * pev[ds * 16 + quad * 4 + 3];
            *(float4*)&Ot[(wv * 16 + n) * 68 + ds * 16 + quad * 4] = ov;
        }
        __syncthreads();
        {
            int r = tid >> 2, c0 = (tid & 3) * 16;
            float* dst = obh + (size_t)(qt * 64 + r) * Dc + c0;
            *(float4*)(dst)      = *(float4*)&Ot[r * 68 + c0];
            *(float4*)(dst + 4)  = *(float4*)&Ot[r * 68 + c0 + 4];
            *(float4*)(dst + 8)  = *(float4*)&Ot[r * 68 + c0 + 8];
            *(float4*)(dst + 12) = *(float4*)&Ot[r * 68 + c0 + 12];
        }
    }
}

extern "C" void kernel_launch(void* const* d_in, const int* in_sizes, int n_in,
                              void* d_out, int out_size, void* d_ws, size_t ws_size,
                              hipStream_t stream)
{
    const float* Q   = (const float*)d_in[0];
    const float* K   = (const float*)d_in[1];
    const float* V   = (const float*)d_in[2];
    const float* pek = (const float*)d_in[3];
    const float* pev = (const float*)d_in[4];
    float* out  = (float*)d_out;
    float* pbuf = out + (size_t)64 * Sc * Dc;   // p_attn follows output

    dim3 grid(8, 64);   // paired q-tiles (b, 15-b): uniform work per block
    relattn<<<grid, 256, 0, stream>>>(Q, K, V, pek, pev, out, pbuf);
}

// Round 13
// 373.630 us; speedup vs baseline: 1.1011x; 1.0109x over previous
//
#include <hip/hip_runtime.h>
#include <math.h>

typedef __attribute__((ext_vector_type(8))) short bfrag;
typedef __attribute__((ext_vector_type(4))) float ffrag;

namespace {
constexpr int Sc = 1024, Dc = 64;
constexpr int P2 = 72;          // bf16 LDS pitch (144 B) for MFMA-read tiles
constexpr int PQ = 64;          // Qs pitch — hoist read is one-time, no pad needed
constexpr int PW = 33;          // f32 pitch for Ts/Ws — bank-spread for row reads
constexpr float SCALE = 0.125f; // 1/sqrt(64)
constexpr float S2 = 0.125f * 1.44269504088896f; // SCALE * log2(e): exp(x*SCALE)=exp2(x*S2)
}

__device__ __forceinline__ unsigned short f2bf(float f) {
    unsigned u = __builtin_bit_cast(unsigned, f);
    u += 0x7fffu + ((u >> 16) & 1u);
    return (unsigned short)(u >> 16);
}
__device__ __forceinline__ bfrag pack8(float4 a, float4 b) {
    bfrag r;
    r[0] = (short)f2bf(a.x); r[1] = (short)f2bf(a.y);
    r[2] = (short)f2bf(a.z); r[3] = (short)f2bf(a.w);
    r[4] = (short)f2bf(b.x); r[5] = (short)f2bf(b.y);
    r[6] = (short)f2bf(b.z); r[7] = (short)f2bf(b.w);
    return r;
}
#define MFMA(a, b, c) __builtin_amdgcn_mfma_f32_16x16x32_bf16((a), (b), (c), 0, 0, 0)

// Paired q-tiles (512 blocks, balanced). Pass 2 software-pipelined to ONE
// barrier per kt: window kt = { QK(kt) -> Pt[kt&1] | stage K[kt+1],V[kt] |
// PV(kt-1)+dump(kt-1) from Pt/Vt[(kt-1)&1] }.
// This revision (kernel is LDS-pipe-bound): dump reads Pt as b64 (4 ops, was
// 8 b32), and exp folded to exp2f(fma(c,S2,ts2)) (saves 2 VALU/exp).
__global__ __launch_bounds__(256, 2)
void relattn(const float* __restrict__ Qg, const float* __restrict__ Kg,
             const float* __restrict__ Vg, const float* __restrict__ pek,
             const float* __restrict__ pev, float* __restrict__ outg,
             float* __restrict__ pbuf)
{
    // LDS arena (72448 B, 2 blocks/CU):
    // Ks0 9216 | Ks1 9216 | Vt0 9216 | Vt1 9216 | Pt0 9216 | Pt1 9216 |
    // Ts 8448 | QsArena 8704 (Qs [64][64] bf16 aliased by Ws [64][33] f32 + W0 [64])
    // Ot (64x68 f32 = 17408 B) aliases Ks0+Ks1 (epilogue only).
    __shared__ __align__(16) char smem[72448];
    unsigned short* Ks0 = (unsigned short*)smem;
    unsigned short* Ks1 = (unsigned short*)(smem + 9216);
    unsigned short* Vt0 = (unsigned short*)(smem + 18432);
    unsigned short* Vt1 = (unsigned short*)(smem + 27648);
    unsigned short* Pt0 = (unsigned short*)(smem + 36864);
    unsigned short* Pt1 = (unsigned short*)(smem + 46080);
    float* Ts = (float*)(smem + 55296);                    // [64][33]
    unsigned short* Qs = (unsigned short*)(smem + 63744);  // [64][64]
    float* Ws = (float*)(smem + 63744);                    // [64][33], aliases Qs
    float* W0 = (float*)(smem + 72192);                    // [64]
    float* Ot = (float*)smem;                              // [64][68], aliases Ks0+Ks1

    const int tid  = threadIdx.x;
    const int bh   = blockIdx.y;
    const int wv   = tid >> 6;
    const int lane = tid & 63;
    const int n    = lane & 15;
    const int quad = lane >> 4;

    const float* Qbh = Qg + (size_t)bh * Sc * Dc;
    const float* Kbh = Kg + (size_t)bh * Sc * Dc;
    const float* Vbh = Vg + (size_t)bh * Sc * Dc;
    float* pbh = pbuf + (size_t)bh * Sc * Sc;
    float* obh = outg + (size_t)bh * Sc * Dc;

    const int sr  = tid >> 2;           // staging row 0..63
    const int sc4 = (tid & 3) * 16;     // staging col (floats)
    const int kp  = tid & 31;           // V-transpose k-pair
    const int vd0 = (tid >> 5) * 8;     // V-transpose d base

    // dump-phase coords: thread owns float4 col c4 of rows {rr, 16+rr, 32+rr, 48+rr}
    const int rr = tid >> 4;            // 0..15
    const int c4 = tid & 15;            // 0..15 (float4 col)

    for (int half = 0; half < 2; ++half) {
        const int qt = half ? (15 - (int)blockIdx.x) : (int)blockIdx.x;
        const int qrow = wv * 16 + quad * 4;   // C-layout row base for this lane

        __syncthreads();   // previous half's epilogue fully done with LDS

        // ---- issue K[0] loads first (latency hides under Q/pe_k staging + Ts) ----
        float4 k0a, k0b, k0c, k0d;
        {
            const float* ksrc = Kbh + (size_t)sr * Dc + sc4;
            k0a = *(const float4*)(ksrc);
            k0b = *(const float4*)(ksrc + 4);
            k0c = *(const float4*)(ksrc + 8);
            k0d = *(const float4*)(ksrc + 12);
        }
        // ---- stage Q tile (fp32 -> bf16) ----
        {
            const float* src = Qbh + (size_t)(qt * 64 + sr) * Dc + sc4;
            float4 a = *(const float4*)(src);
            float4 b = *(const float4*)(src + 4);
            float4 c = *(const float4*)(src + 8);
            float4 d = *(const float4*)(src + 12);
            *(bfrag*)&Qs[sr * PQ + sc4]     = pack8(a, b);
            *(bfrag*)&Qs[sr * PQ + sc4 + 8] = pack8(c, d);
        }
        // ---- stage pe_k (rows 0..32) into Ks0; zero rows 33..47 ----
        for (int i = tid; i < 135; i += 256) {          // zero [33*72, 48*72)
            bfrag z = {};
            *(bfrag*)&Ks0[33 * P2 + i * 8] = z;
        }
        if (tid < 132) {
            int r = tid >> 2, c0 = (tid & 3) * 16;
            const float* src = pek + (size_t)r * Dc + c0;
            float4 a = *(const float4*)(src);
            float4 b = *(const float4*)(src + 4);
            float4 c = *(const float4*)(src + 8);
            float4 d = *(const float4*)(src + 12);
            *(bfrag*)&Ks0[r * P2 + c0]     = pack8(a, b);
            *(bfrag*)&Ks0[r * P2 + c0 + 8] = pack8(c, d);
        }
        __syncthreads();

        // ---- hoist Q A-frags (row = wv*16+n, k = d); Qs dead afterwards ----
        bfrag qa0 = *(bfrag*)&Qs[(wv * 16 + n) * PQ + quad * 8];
        bfrag qa1 = *(bfrag*)&Qs[(wv * 16 + n) * PQ + 32 + quad * 8];

        // ---- Ts = Q . pe_k^T via MFMA (j in 0..47, keep j<=32) ----
        #pragma unroll
        for (int sub = 0; sub < 3; ++sub) {
            bfrag b0 = *(bfrag*)&Ks0[(sub * 16 + n) * P2 + quad * 8];
            bfrag b1 = *(bfrag*)&Ks0[(sub * 16 + n) * P2 + 32 + quad * 8];
            ffrag c = {};
            c = MFMA(qa0, b0, c);
            c = MFMA(qa1, b1, c);
            int j = sub * 16 + n;
            if (j <= 32) {
                #pragma unroll
                for (int reg = 0; reg < 4; ++reg)
                    Ts[(qrow + reg) * PW + j] = c[reg];
            }
        }
        // ---- pack K[0] -> Ks1 (waits k0*); issue K[1] prefetch ----
        *(bfrag*)&Ks1[sr * P2 + sc4]     = pack8(k0a, k0b);
        *(bfrag*)&Ks1[sr * P2 + sc4 + 8] = pack8(k0c, k0d);
        float4 pka, pkb, pkc, pkd;
        if (qt >= 1) {
            const float* ksrc = Kbh + (size_t)(64 + sr) * Dc + sc4;
            pka = *(const float4*)(ksrc);
            pkb = *(const float4*)(ksrc + 4);
            pkc = *(const float4*)(ksrc + 8);
            pkd = *(const float4*)(ksrc + 12);
        }
        __syncthreads();   // Ts + K[0] visible; all waves hoisted Q -> Qs free

        float ts2[4];   // pre-scaled for exp2: exp((c+ts0)*SCALE) = exp2(fma(c,S2,ts2))
        #pragma unroll
        for (int reg = 0; reg < 4; ++reg) ts2[reg] = Ts[(qrow + reg) * PW] * S2;

        // ---- zero Ws (aliases Qs; safe after barrier) ----
        for (int idx = tid; idx < 64 * PW; idx += 256) Ws[idx] = 0.f;

        // ---- zero-fill fully-masked p region (cols >= (qt+1)*64) ----
        {
            const int zb = (qt + 1) * 64;
            if (zb < Sc) {
                const int z4 = (Sc - zb) >> 2;
                const float4 z = make_float4(0.f, 0.f, 0.f, 0.f);
                for (int r = 0; r < 64; ++r) {
                    float4* rp = (float4*)(pbh + (size_t)(qt * 64 + r) * Sc + zb);
                    for (int cz = tid; cz < z4; cz += 256) rp[cz] = z;
                }
            }
        }

        // ================= pass 1: l = sum(exp(s)), 1 barrier/kt =================
        float lsum[4] = {0.f, 0.f, 0.f, 0.f};
        for (int kt = 0; kt <= qt; ++kt) {
            const bool bnd = (kt >= qt - 1);
            unsigned short* Kc = (kt & 1) ? Ks0 : Ks1;   // K[0] lives in Ks1
            unsigned short* Kn = (kt & 1) ? Ks1 : Ks0;
            #pragma unroll
            for (int sub = 0; sub < 4; ++sub) {
                bfrag b0 = *(bfrag*)&Kc[(sub * 16 + n) * P2 + quad * 8];
                bfrag b1 = *(bfrag*)&Kc[(sub * 16 + n) * P2 + 32 + quad * 8];
                ffrag c = {};
                c = MFMA(qa0, b0, c);
                c = MFMA(qa1, b1, c);
                const int k = kt * 64 + sub * 16 + n;
                if (!bnd) {
                    #pragma unroll
                    for (int reg = 0; reg < 4; ++reg)
                        lsum[reg] += exp2f(fmaf(c[reg], S2, ts2[reg]));
                } else {
                    #pragma unroll
                    for (int reg = 0; reg < 4; ++reg) {
                        int jrel = k - (qt * 64 + qrow + reg) + 32;
                        if (jrel <= 32) {
                            int jcl = jrel < 0 ? 0 : jrel;
                            lsum[reg] += exp2f(fmaf(c[reg] + Ts[(qrow + reg) * PW + jcl], S2, 0.f));
                        }
                    }
                }
            }
            if (kt < qt) {     // stage K[kt+1] (regs prefetched last iter)
                *(bfrag*)&Kn[sr * P2 + sc4]     = pack8(pka, pkb);
                *(bfrag*)&Kn[sr * P2 + sc4 + 8] = pack8(pkc, pkd);
            }
            if (kt + 2 <= qt) {   // issue K[kt+2]
                const float* ksrc = Kbh + (size_t)((kt + 2) * 64 + sr) * Dc + sc4;
                pka = *(const float4*)(ksrc);
                pkb = *(const float4*)(ksrc + 4);
                pkc = *(const float4*)(ksrc + 8);
                pkd = *(const float4*)(ksrc + 12);
            }
            __syncthreads();
        }
        float rinv[4];
        #pragma unroll
        for (int reg = 0; reg < 4; ++reg) {
            float l = lsum[reg];
            l += __shfl_xor(l, 1);
            l += __shfl_xor(l, 2);
            l += __shfl_xor(l, 4);
            l += __shfl_xor(l, 8);
            rinv[reg] = 1.f / l;
        }

        // ---- pass-2 prologue: restage K[0]->Ks0 (L2-hot); issue K[1], V[0] ----
        {
            const float* ksrc = Kbh + (size_t)sr * Dc + sc4;
            float4 a = *(const float4*)(ksrc);
            float4 b = *(const float4*)(ksrc + 4);
            float4 c = *(const float4*)(ksrc + 8);
            float4 d = *(const float4*)(ksrc + 12);
            *(bfrag*)&Ks0[sr * P2 + sc4]     = pack8(a, b);
            *(bfrag*)&Ks0[sr * P2 + sc4 + 8] = pack8(c, d);
        }
        if (qt >= 1) {
            const float* ksrc = Kbh + (size_t)(64 + sr) * Dc + sc4;
            pka = *(const float4*)(ksrc);
            pkb = *(const float4*)(ksrc + 4);
            pkc = *(const float4*)(ksrc + 8);
            pkd = *(const float4*)(ksrc + 12);
        }
        float4 pva, pvb, pvc, pvd;
        {
            const float* vsrc = Vbh + (size_t)(2 * kp) * Dc + vd0;
            pva = *(const float4*)(vsrc);
            pvb = *(const float4*)(vsrc + 4);
            pvc = *(const float4*)(vsrc + Dc);
            pvd = *(const float4*)(vsrc + Dc + 4);
        }
        __syncthreads();   // K[0] visible

        // ====== pass 2 (pipelined, 1 barrier/kt): QK(kt) || PV(kt-1)+dump ======
        ffrag oacc[4];
        #pragma unroll
        for (int i = 0; i < 4; ++i) { ffrag z = {}; oacc[i] = z; }

        for (int kt = 0; kt <= qt; ++kt) {
            const bool bnd = (kt >= qt - 1);
            unsigned short* Kc  = (kt & 1) ? Ks1 : Ks0;   // K[kt] (K[0] in Ks0)
            unsigned short* Kn  = (kt & 1) ? Ks0 : Ks1;
            unsigned short* Vc  = (kt & 1) ? Vt1 : Vt0;   // stage target for V[kt]
            unsigned short* Vp  = (kt & 1) ? Vt0 : Vt1;   // V[kt-1] for PV
            unsigned short* Ptc = (kt & 1) ? Pt1 : Pt0;   // QK(kt) writes
            unsigned short* Ptp = (kt & 1) ? Pt0 : Pt1;   // PV(kt-1) reads

            // ---- QK(kt): scores -> Ptc (bf16, normalized), rel-v capture ----
            #pragma unroll
            for (int sub = 0; sub < 4; ++sub) {
                bfrag b0 = *(bfrag*)&Kc[(sub * 16 + n) * P2 + quad * 8];
                bfrag b1 = *(bfrag*)&Kc[(sub * 16 + n) * P2 + 32 + quad * 8];
                ffrag c = {};
                c = MFMA(qa0, b0, c);
                c = MFMA(qa1, b1, c);
                const int k = kt * 64 + sub * 16 + n;
                if (!bnd) {
                    #pragma unroll
                    for (int reg = 0; reg < 4; ++reg) {
                        float p = exp2f(fmaf(c[reg], S2, ts2[reg])) * rinv[reg];
                        Ptc[(qrow + reg) * P2 + sub * 16 + n] = (unsigned short)f2bf(p);
                    }
                } else {
                    #pragma unroll
                    for (int reg = 0; reg < 4; ++reg) {
                        int jrel = k - (qt * 64 + qrow + reg) + 32;
                        float p = 0.f;
                        if (jrel <= 32) {
                            int jcl = jrel < 0 ? 0 : jrel;
                            p = exp2f((c[reg] + Ts[(qrow + reg) * PW + jcl]) * S2) * rinv[reg];
                        }
                        Ptc[(qrow + reg) * P2 + sub * 16 + n] = (unsigned short)f2bf(p);
                        if ((unsigned)(jrel - 1) < 32u) Ws[(qrow + reg) * PW + jrel - 1] = p;
                    }
                }
            }
            // ---- stage K[kt+1] -> Kn; V[kt] -> Vc (regs from last window) ----
            if (kt < qt) {
                *(bfrag*)&Kn[sr * P2 + sc4]     = pack8(pka, pkb);
                *(bfrag*)&Kn[sr * P2 + sc4 + 8] = pack8(pkc, pkd);
            }
            {
                float r0[8] = {pva.x, pva.y, pva.z, pva.w, pvb.x, pvb.y, pvb.z, pvb.w};
                float r1[8] = {pvc.x, pvc.y, pvc.z, pvc.w, pvd.x, pvd.y, pvd.z, pvd.w};
                #pragma unroll
                for (int i = 0; i < 8; ++i) {
                    unsigned pk = (unsigned)f2bf(r0[i]) | ((unsigned)f2bf(r1[i]) << 16);
                    *(unsigned*)&Vc[(vd0 + i) * P2 + 2 * kp] = pk;   // Vc[d][k]
                }
            }
            // ---- issue next prefetches ----
            if (kt + 2 <= qt) {
                const float* ksrc = Kbh + (size_t)((kt + 2) * 64 + sr) * Dc + sc4;
                pka = *(const float4*)(ksrc);
                pkb = *(const float4*)(ksrc + 4);
                pkc = *(const float4*)(ksrc + 8);
                pkd = *(const float4*)(ksrc + 12);
            }
            if (kt + 1 <= qt) {
                const float* vsrc = Vbh + (size_t)((kt + 1) * 64 + 2 * kp) * Dc + vd0;
                pva = *(const float4*)(vsrc);
                pvb = *(const float4*)(vsrc + 4);
                pvc = *(const float4*)(vsrc + Dc);
                pvd = *(const float4*)(vsrc + Dc + 4);
            }
            // ---- PV(kt-1) + dump(kt-1): independent of QK(kt) ----
            if (kt >= 1) {
                bfrag pb0 = *(bfrag*)&Ptp[(wv * 16 + n) * P2 + quad * 8];
                bfrag pb1 = *(bfrag*)&Ptp[(wv * 16 + n) * P2 + 32 + quad * 8];
                #pragma unroll
                for (int ds = 0; ds < 4; ++ds) {
                    bfrag va0 = *(bfrag*)&Vp[(ds * 16 + n) * P2 + quad * 8];
                    bfrag va1 = *(bfrag*)&Vp[(ds * 16 + n) * P2 + 32 + quad * 8];
                    oacc[ds] = MFMA(va0, pb0, oacc[ds]);
                    oacc[ds] = MFMA(va1, pb1, oacc[ds]);
                }
                float* base = pbh + ((size_t)(qt * 64 + rr) * Sc + (kt - 1) * 64 + c4 * 4);
                #pragma unroll
                for (int step = 0; step < 4; ++step) {
                    const int r = step * 16 + rr;
                    uint2 two = *(const uint2*)&Ptp[r * P2 + c4 * 4];   // ds_read_b64
                    float4 v;
                    v.x = __builtin_bit_cast(float, (two.x & 0xffffu) << 16);
                    v.y = __builtin_bit_cast(float, two.x & 0xffff0000u);
                    v.z = __builtin_bit_cast(float, (two.y & 0xffffu) << 16);
                    v.w = __builtin_bit_cast(float, two.y & 0xffff0000u);
                    *(float4*)(base + (size_t)(step * 16) * Sc) = v;
                }
            }
            __syncthreads();   // window boundary
        }
        // ---- drain: PV(qt) + dump(qt) ----
        {
            unsigned short* Ptp = (qt & 1) ? Pt1 : Pt0;
            unsigned short* Vp  = (qt & 1) ? Vt1 : Vt0;
            bfrag pb0 = *(bfrag*)&Ptp[(wv * 16 + n) * P2 + quad * 8];
            bfrag pb1 = *(bfrag*)&Ptp[(wv * 16 + n) * P2 + 32 + quad * 8];
            #pragma unroll
            for (int ds = 0; ds < 4; ++ds) {
                bfrag va0 = *(bfrag*)&Vp[(ds * 16 + n) * P2 + quad * 8];
                bfrag va1 = *(bfrag*)&Vp[(ds * 16 + n) * P2 + 32 + quad * 8];
                oacc[ds] = MFMA(va0, pb0, oacc[ds]);
                oacc[ds] = MFMA(va1, pb1, oacc[ds]);
            }
            float* base = pbh + ((size_t)(qt * 64 + rr) * Sc + qt * 64 + c4 * 4);
            #pragma unroll
            for (int step = 0; step < 4; ++step) {
                const int r = step * 16 + rr;
                uint2 two = *(const uint2*)&Ptp[r * P2 + c4 * 4];   // ds_read_b64
                float4 v;
                v.x = __builtin_bit_cast(float, (two.x & 0xffffu) << 16);
                v.y = __builtin_bit_cast(float, two.x & 0xffff0000u);
                v.z = __builtin_bit_cast(float, (two.y & 0xffffu) << 16);
                v.w = __builtin_bit_cast(float, two.y & 0xffff0000u);
                *(float4*)(base + (size_t)(step * 16) * Sc) = v;
            }
        }
        __syncthreads();   // all PV/dump reads done before epilogue prep writes

        // ================= epilogue: rel-v term + store O =================
        if (tid < 64) {
            float s = 0.f;
            #pragma unroll
            for (int j = 0; j < 32; ++j) s += Ws[tid * PW + j];   // pitch-33: conflict-free
            W0[tid] = 1.f - s;   // mass of far past (jrel<=0)
        }
        {   // Pt0[q][jj] <- Ws (bf16), jj = jrel-1 in 0..31
            int q = tid >> 2, j0 = (tid & 3) * 8;
            #pragma unroll
            for (int i = 0; i < 8; i += 2) {
                unsigned pk = (unsigned)f2bf(Ws[q * PW + j0 + i]) |
                              ((unsigned)f2bf(Ws[q * PW + j0 + i + 1]) << 16);
                *(unsigned*)&Pt0[q * P2 + j0 + i] = pk;
            }
        }
        {   // Vt0[d][jj] <- pe_v[jj+1][d]
            int jj = tid >> 3, d0 = (tid & 7) * 8;
            const float* src = pev + (size_t)(jj + 1) * Dc + d0;
            float4 a = *(const float4*)(src);
            float4 b = *(const float4*)(src + 4);
            float vr[8] = {a.x, a.y, a.z, a.w, b.x, b.y, b.z, b.w};
            #pragma unroll
            for (int i = 0; i < 8; ++i)
                Vt0[(d0 + i) * P2 + jj] = (unsigned short)f2bf(vr[i]);
        }
        __syncthreads();   // Pt0/Vt0/W0 prep visible
        {
            bfrag pb = *(bfrag*)&Pt0[(wv * 16 + n) * P2 + quad * 8];
            #pragma unroll
            for (int ds = 0; ds < 4; ++ds) {
                bfrag va = *(bfrag*)&Vt0[(ds * 16 + n) * P2 + quad * 8];
                oacc[ds] = MFMA(va, pb, oacc[ds]);
            }
        }
        float w0q = W0[wv * 16 + n];
        // Ot aliases Ks0/Ks1 only (dead) — no barrier needed before write
        #pragma unroll
        for (int ds = 0; ds < 4; ++ds) {
            float4 ov;
            ov.x = oacc[ds][0] + w0q * pev[ds * 16 + quad * 4 + 0];
            ov.y = oacc[ds][1] + w0q * pev[ds * 16 + quad * 4 + 1];
            ov.z = oacc[ds][2] + w0q * pev[ds * 16 + quad * 4 + 2];
            ov.w = oacc[ds][3] + w0q * pev[ds * 16 + quad * 4 + 3];
            *(float4*)&Ot[(wv * 16 + n) * 68 + ds * 16 + quad * 4] = ov;
        }
        __syncthreads();
        {
            int r = tid >> 2, c0 = (tid & 3) * 16;
            float* dst = obh + (size_t)(qt * 64 + r) * Dc + c0;
            *(float4*)(dst)      = *(float4*)&Ot[r * 68 + c0];
            *(float4*)(dst + 4)  = *(float4*)&Ot[r * 68 + c0 + 4];
            *(float4*)(dst + 8)  = *(float4*)&Ot[r * 68 + c0 + 8];
            *(float4*)(dst + 12) = *(float4*)&Ot[r * 68 + c0 + 12];
        }
    }
}

extern "C" void kernel_launch(void* const* d_in, const int* in_sizes, int n_in,
                              void* d_out, int out_size, void* d_ws, size_t ws_size,
                              hipStream_t stream)
{
    const float* Q   = (const float*)d_in[0];
    const float* K   = (const float*)d_in[1];
    const float* V   = (const float*)d_in[2];
    const float* pek = (const float*)d_in[3];
    const float* pev = (const float*)d_in[4];
    float* out  = (float*)d_out;
    float* pbuf = out + (size_t)64 * Sc * Dc;   // p_attn follows output

    dim3 grid(8, 64);   // paired q-tiles (b, 15-b): uniform work per block
    relattn<<<grid, 256, 0, stream>>>(Q, K, V, pek, pev, out, pbuf);
}